// Round 13
// baseline (458.093 us; speedup 1.0000x reference)
//
#include <hip/hip_runtime.h>
#include <hip/hip_bf16.h>
#include <hip/hip_fp16.h>

#define NN 100000
#define EE 800000
#define GG 128

typedef short bf16x8 __attribute__((ext_vector_type(8)));
typedef float f32x4 __attribute__((ext_vector_type(4)));
typedef float f32x2 __attribute__((ext_vector_type(2)));

__device__ __forceinline__ float bf2f(unsigned short v) {
    union { unsigned int u; float f; } x; x.u = ((unsigned int)v) << 16; return x.f;
}
__device__ __forceinline__ unsigned short f2bf(float f) {
    union { float f; unsigned int u; } x; x.f = f;
    unsigned int r = x.u + 0x7fffu + ((x.u >> 16) & 1u);
    return (unsigned short)(r >> 16);
}
__device__ __forceinline__ float sigmoidf_(float x) { return 1.f / (1.f + __expf(-x)); }
__device__ __forceinline__ float ldp(const void* p, int i, int f) {
    return f ? ((const float*)p)[i] : bf2f(((const unsigned short*)p)[i]);
}

// ---------------- fp8 helpers ----------------
#if defined(__has_builtin)
#if __has_builtin(__builtin_amdgcn_cvt_pk_f32_fp8) && __has_builtin(__builtin_amdgcn_cvt_pk_fp8_f32)
#define USE_HW_FP8 1
#endif
#endif
#ifndef USE_HW_FP8
#define USE_HW_FP8 0
#endif

#if USE_HW_FP8
__device__ __forceinline__ int fp8_pack2(float a, float b) {
    return __builtin_amdgcn_cvt_pk_fp8_f32(a, b, 0, false);
}
__device__ __forceinline__ void fp8_dec4v(unsigned int q, f32x2& lo, f32x2& hi) {
    lo = __builtin_amdgcn_cvt_pk_f32_fp8((int)q, false);
    hi = __builtin_amdgcn_cvt_pk_f32_fp8((int)q, true);
}
#else
__device__ __forceinline__ unsigned char f2bf8(float f) {
    unsigned short u = __half_as_ushort(__float2half(f));
    unsigned short r = u + 0x7f + ((u >> 8) & 1);
    return (unsigned char)(r >> 8);
}
__device__ __forceinline__ int fp8_pack2(float a, float b) {
    return (int)f2bf8(a) | ((int)f2bf8(b) << 8);
}
__device__ __forceinline__ float bf8_dec(unsigned int b) {
    return __half2float(__ushort_as_half((unsigned short)(b << 8)));
}
__device__ __forceinline__ void fp8_dec4v(unsigned int q, f32x2& lo, f32x2& hi) {
    lo[0] = bf8_dec(q & 0xff); lo[1] = bf8_dec((q >> 8) & 0xff);
    hi[0] = bf8_dec((q >> 16) & 0xff); hi[1] = bf8_dec(q >> 24);
}
#endif

// ---------------- merged dtype probes ----------------
__global__ void k_probe2(const unsigned int* __restrict__ w, const int* __restrict__ ei,
                         int* __restrict__ fflag, int* __restrict__ iflag) {
    __shared__ int s[256];
    int t = threadIdx.x;
    if (blockIdx.x == 0) {
        int cnt = 0;
        for (int i = t; i < 1024; i += 256) {
            unsigned int v = w[i];
            int e = (v >> 7) & 0xff;
            cnt += (e >= 100 && e <= 127) ? 1 : 0;
        }
        s[t] = cnt; __syncthreads();
        for (int d = 128; d > 0; d >>= 1) { if (t < d) s[t] += s[t + d]; __syncthreads(); }
        if (t == 0) fflag[0] = (s[0] >= 512) ? 0 : 1;
    } else {
        int nz = 0;
        for (int i = t; i < 1024; i += 256) nz |= ei[2 * i + 1];
        s[t] = nz; __syncthreads();
        for (int d = 128; d > 0; d >>= 1) { if (t < d) s[t] |= s[t + d]; __syncthreads(); }
        if (t == 0) iflag[0] = (s[0] == 0) ? 1 : 0;
    }
}

// ---------------- int normalization + fused dst histogram ----------------
__global__ void k_cvt(const int* __restrict__ xi, const int* __restrict__ ei,
                      const int* __restrict__ bi, const int* __restrict__ flag,
                      int* __restrict__ xn, int* __restrict__ srcn,
                      int* __restrict__ dstn, int* __restrict__ batchn,
                      int* __restrict__ count) {
    int j = blockIdx.x * 256 + threadIdx.x;
    int f = flag[0];
    const int XT = NN * 6, ET = 2 * EE;
    if (j < XT) xn[j] = f ? xi[2 * j] : xi[j];
    int je = j - XT;
    if (je >= 0 && je < ET) {
        int v = f ? ei[2 * je] : ei[je];
        if (je < EE) srcn[je] = v;
        else { dstn[je - EE] = v; atomicAdd(&count[v], 1); }
    }
    int jb = j - XT - ET;
    if (jb >= 0 && jb < NN) batchn[jb] = f ? bi[2 * jb] : bi[jb];
}

// ---------------- counting sort ----------------
__global__ void k_chunk_sum(const int* __restrict__ count, int* __restrict__ csum) {
    __shared__ int s[256];
    int t = threadIdx.x;
    int base = blockIdx.x * 1024 + t * 4;
    int acc = 0;
    #pragma unroll
    for (int j = 0; j < 4; j++) { int n = base + j; if (n < NN) acc += count[n]; }
    s[t] = acc; __syncthreads();
    for (int d = 128; d > 0; d >>= 1) { if (t < d) s[t] += s[t + d]; __syncthreads(); }
    if (t == 0) csum[blockIdx.x] = s[0];
}

__global__ void k_chunk_scan(const int* __restrict__ csum, int* __restrict__ coff, int nchunk) {
    __shared__ int s[256];
    int t = threadIdx.x;
    int v = (t < nchunk) ? csum[t] : 0;
    s[t] = v; __syncthreads();
    for (int d = 1; d < 256; d <<= 1) {
        int x = (t >= d) ? s[t - d] : 0;
        __syncthreads(); s[t] += x; __syncthreads();
    }
    if (t < nchunk) coff[t] = s[t] - v;
}

__global__ void k_scan_write(const int* __restrict__ count, const int* __restrict__ coff,
                             int* __restrict__ offset, int* __restrict__ cursor) {
    __shared__ int s[256];
    int t = threadIdx.x;
    int base = blockIdx.x * 1024 + t * 4;
    int v[4]; int acc = 0;
    #pragma unroll
    for (int j = 0; j < 4; j++) { v[j] = (base + j < NN) ? count[base + j] : 0; acc += v[j]; }
    s[t] = acc; __syncthreads();
    for (int d = 1; d < 256; d <<= 1) {
        int x = (t >= d) ? s[t - d] : 0;
        __syncthreads(); s[t] += x; __syncthreads();
    }
    int pre = s[t] - acc + coff[blockIdx.x];
    #pragma unroll
    for (int j = 0; j < 4; j++) {
        if (base + j < NN) { offset[base + j] = pre; cursor[base + j] = pre; pre += v[j]; }
    }
}

__global__ void k_scatter(const int* __restrict__ src, const int* __restrict__ dst,
                          int* __restrict__ cursor, int* __restrict__ sorted) {
    int e = blockIdx.x * 256 + threadIdx.x;
    if (e < EE) {
        int d = dst[e];
        int p = atomicAdd(&cursor[d], 1);
        sorted[p] = src[e];
    }
}

// ---------------- param conversion (W2T, GWT, vectors; W1/emb handled by P-table) ----------------
__global__ void k_cvtp(const void* W2,
                       const void* as1, const void* ad1, const void* b1,
                       const void* as2, const void* ad2, const void* b2,
                       const void* gw1, const void* gb1,
                       const void* bng, const void* bnb, const void* bnm, const void* bnv,
                       const void* gw2, const void* gb2, const void* glw, const void* glb,
                       const int* __restrict__ fflag,
                       unsigned short* __restrict__ W2T,
                       unsigned short* __restrict__ GWT, float* __restrict__ gb1p,
                       float* __restrict__ vs1, float* __restrict__ vd1,
                       float* __restrict__ vs2, float* __restrict__ vd2,
                       float* __restrict__ vb1, float* __restrict__ vb2,
                       float* __restrict__ gw2f, float* __restrict__ glwf,
                       float* __restrict__ gb2f, float* __restrict__ glbf) {
    int i = blockIdx.x * 256 + threadIdx.x;
    int f = fflag[0];
    if (i < 32768) { int k = i / 256, n = i % 256; W2T[n * 128 + k] = f2bf(ldp(W2, i, f)); }
    if (i < 16384) {
        int n = i >> 7, k = i & 127;
        float sc = ldp(bng, n, f) * rsqrtf(ldp(bnv, n, f) + 1e-5f);
        GWT[i] = f2bf(ldp(gw1, k * 128 + n, f) * sc);
    }
    if (i < 256) {
        vs1[i] = ldp(as1, i, f); vd1[i] = ldp(ad1, i, f);
        vs2[i] = ldp(as2, i, f); vd2[i] = ldp(ad2, i, f);
    }
    if (i < 128) {
        vb1[i] = ldp(b1, i, f); vb2[i] = ldp(b2, i, f);
        gw2f[i] = ldp(gw2, i, f); glwf[i] = ldp(glw, i, f);
        float sc = ldp(bng, i, f) * rsqrtf(ldp(bnv, i, f) + 1e-5f);
        gb1p[i] = (ldp(gb1, i, f) - ldp(bnm, i, f)) * sc + ldp(bnb, i, f);
    }
    if (i == 0) { gb2f[0] = ldp(gb2, 0, f); glbf[0] = ldp(glb, 0, f); }
}

// ---------------- P-table: P[r][c] = sum_k emb_t[v][k] * W1[t*64+k][c]; 50 rows ----------------
__constant__ int c_vbase[7] = {0, 33, 38, 41, 45, 47, 50};
__global__ __launch_bounds__(256) void k_prep_p(
    const void* e0, const void* e1, const void* e2,
    const void* e3, const void* e4, const void* e5,
    const void* W1, const int* __restrict__ fflag,
    float* __restrict__ P) {
    int r = blockIdx.x;          // 0..49
    int c = threadIdx.x;         // 0..255
    int f = fflag[0];
    int t = 0;
    while (r >= c_vbase[t + 1]) t++;
    int v = r - c_vbase[t];
    const void* emb = (t == 0) ? e0 : (t == 1) ? e1 : (t == 2) ? e2 :
                      (t == 3) ? e3 : (t == 4) ? e4 : e5;
    float acc = 0.f;
    #pragma unroll 8
    for (int k = 0; k < 64; k++) {
        acc += ldp(emb, v * 64 + k, f) * ldp(W1, (t * 64 + k) * 256 + c, f);
    }
    P[r * 256 + c] = acc;
}

// ---------------- layer-1: H = sum_t P[x_t] (one wave per node) + fused al + fp8 store ----------------
__global__ __launch_bounds__(256) void k_embsum(
    const int* __restrict__ xn, const float* __restrict__ P,
    const float* __restrict__ avs, const float* __restrict__ avd,
    unsigned char* __restrict__ H8,
    float* __restrict__ alS, float* __restrict__ alD) {
    int node = blockIdx.x * 4 + (threadIdx.x >> 6);
    if (node >= NN) return;
    int lane = threadIdx.x & 63;
    int c0 = lane * 4;
    int ix[6];
    #pragma unroll
    for (int t = 0; t < 6; t++) ix[t] = (c_vbase[t] + xn[node * 6 + t]) * 256 + c0;
    float4 a = *(const float4*)(P + ix[0]);
    #pragma unroll
    for (int t = 1; t < 6; t++) {
        float4 b = *(const float4*)(P + ix[t]);
        a.x += b.x; a.y += b.y; a.z += b.z; a.w += b.w;
    }
    // fused attention coefficients (head0 = lanes 0..31, head1 = lanes 32..63)
    float4 sv = *(const float4*)(avs + c0);
    float4 dv = *(const float4*)(avd + c0);
    float ps = a.x * sv.x + a.y * sv.y + a.z * sv.z + a.w * sv.w;
    float pd = a.x * dv.x + a.y * dv.y + a.z * dv.z + a.w * dv.w;
    #pragma unroll
    for (int m = 1; m < 32; m <<= 1) {
        ps += __shfl_xor(ps, m);
        pd += __shfl_xor(pd, m);
    }
    if ((lane & 31) == 0) {
        int head = lane >> 5;
        alS[node * 2 + head] = ps;
        alD[node * 2 + head] = pd;
    }
    // fp8 store (byte c = channel c)
    unsigned int u = ((unsigned)fp8_pack2(a.x, a.y) & 0xffffu) |
                     ((unsigned)fp8_pack2(a.z, a.w) << 16);
    *(unsigned int*)(H8 + (size_t)node * 256 + c0) = u;
}

// ---------------- MFMA GEMM (layer 2 only): M=64 tile, swizzled LDS ----------------
__global__ __launch_bounds__(256, 2) void k_gemm(
    const unsigned short* __restrict__ Ain,
    const unsigned short* __restrict__ WT, unsigned char* __restrict__ H8,
    const float* __restrict__ avs, const float* __restrict__ avd,
    float* __restrict__ alS, float* __restrict__ alD,
    int K)
{
    __shared__ __align__(16) unsigned short As[64 * 32];
    __shared__ __align__(16) unsigned short Bs[256 * 32];
    int tid = threadIdx.x;
    int wave = tid >> 6, lane = tid & 63;
    int quad = lane >> 4, lr = lane & 15;
    int m0 = blockIdx.x * 64;

    f32x4 zero4 = {0.f, 0.f, 0.f, 0.f};
    f32x4 acc[16];
    #pragma unroll
    for (int j = 0; j < 16; j++) acc[j] = zero4;

    for (int k0 = 0; k0 < K; k0 += 32) {
        {
            int row = tid >> 2, part = tid & 3;
            int gr = m0 + row; if (gr >= NN) gr = NN - 1;
            int g = ((row >> 4) << 6) + (part << 4) + (row & 15);
            g ^= (part << 1);
            *(uint4*)(&As[g * 8]) = *(const uint4*)(Ain + (size_t)gr * K + k0 + part * 8);
        }
        #pragma unroll
        for (int i = 0; i < 4; i++) {
            int idx = tid + i * 256;
            int row = idx >> 2, part = idx & 3;
            int g = ((row >> 4) << 6) + (part << 4) + (row & 15);
            g ^= (part << 1);
            *(uint4*)(&Bs[g * 8]) =
                *(const uint4*)(WT + (size_t)row * K + k0 + part * 8);
        }
        __syncthreads();

        int sw = (quad << 1);
        bf16x8 af0 = *(const bf16x8*)(&As[((wave * 64 + lane) ^ sw) * 8]);
        #pragma unroll
        for (int ni = 0; ni < 16; ni++) {
            bf16x8 bfv = *(const bf16x8*)(&Bs[((ni * 64 + lane) ^ sw) * 8]);
            acc[ni] = __builtin_amdgcn_mfma_f32_16x16x32_bf16(af0, bfv, acc[ni], 0, 0, 0);
        }
        __syncthreads();
    }

    float svv[16], dvv[16];
    #pragma unroll
    for (int ni = 0; ni < 16; ni++) { svv[ni] = avs[ni * 16 + lr]; dvv[ni] = avd[ni * 16 + lr]; }
    #pragma unroll
    for (int r = 0; r < 4; r++) {
        int grow = m0 + wave * 16 + quad * 4 + r;
        float ps0 = 0.f, ps1 = 0.f, pd0 = 0.f, pd1 = 0.f;
        if (grow < NN) {
            #pragma unroll
            for (int ni = 0; ni < 16; ni += 2) {
                float v0 = acc[ni][r], v1 = acc[ni + 1][r];
                int pk = fp8_pack2(v0, v1);
                H8[(size_t)grow * 256 + ni * 16 + lr] = (unsigned char)(pk & 0xff);
                H8[(size_t)grow * 256 + (ni + 1) * 16 + lr] = (unsigned char)((pk >> 8) & 0xff);
                if (ni < 8) { ps0 += v0 * svv[ni] + v1 * svv[ni + 1]; pd0 += v0 * dvv[ni] + v1 * dvv[ni + 1]; }
                else        { ps1 += v0 * svv[ni] + v1 * svv[ni + 1]; pd1 += v0 * dvv[ni] + v1 * dvv[ni + 1]; }
            }
        }
        #pragma unroll
        for (int m = 1; m < 16; m <<= 1) {
            ps0 += __shfl_xor(ps0, m); ps1 += __shfl_xor(ps1, m);
            pd0 += __shfl_xor(pd0, m); pd1 += __shfl_xor(pd1, m);
        }
        if (lr == 0 && grow < NN) {
            alS[grow * 2 + 0] = ps0; alS[grow * 2 + 1] = ps1;
            alD[grow * 2 + 0] = pd0; alD[grow * 2 + 1] = pd1;
        }
    }
}

// ---------------- fused edge-weight + segment aggregation (one wave per dst) ----------------
__device__ __forceinline__ float edge_w(float e) {
    e = e > 0.f ? e : 0.2f * e;
    e = fminf(fmaxf(e, -60.f), 60.f);
    return __expf(e);
}
__global__ __launch_bounds__(256) void k_agg(const unsigned char* __restrict__ H8,
                                             const float* __restrict__ alS, const float* __restrict__ alD,
                                             const int* __restrict__ sorted, const int* __restrict__ offs,
                                             const int* __restrict__ cnts,
                                             const float* __restrict__ bias,
                                             unsigned short* __restrict__ Out) {
    __shared__ uint4 lw[4][64];
    int wid = threadIdx.x >> 6;
    int node = blockIdx.x * 4 + wid;
    if (node >= NN) return;
    int lane = threadIdx.x & 63;
    int head = lane >> 5;
    float2 adv = *(const float2*)(alD + node * 2);
    float myAd = head ? adv.y : adv.x;
    const unsigned char* Hl = H8 + lane * 4;

    float ws = edge_w(alS[node * 2 + head] + myAd);
    unsigned int qv = *(const unsigned int*)(Hl + ((unsigned)node << 8));
    f32x2 lo, hi; fp8_dec4v(qv, lo, hi);
    float den = ws;
    f32x2 wsv = {ws, ws};
    f32x2 n01 = lo * wsv, n23 = hi * wsv;

    int off = offs[node], cnt = cnts[node];
    for (int c = 0; c < cnt; c += 64) {
        int m = cnt - c; if (m > 64) m = 64;
        int j = off + c + (lane < m ? lane : 0);
        int s = sorted[j];
        float2 asv = *(const float2*)(alS + s * 2);
        float w0 = edge_w(asv.x + adv.x);
        float w1 = edge_w(asv.y + adv.y);
        lw[wid][lane] = make_uint4((unsigned)s << 8, __float_as_uint(w0), __float_as_uint(w1), 0u);
        int i = 0;
        for (; i + 8 <= m; i += 8) {
            uint4 e[8];
            #pragma unroll
            for (int u = 0; u < 8; u++) e[u] = lw[wid][i + u];
            unsigned q[8];
            #pragma unroll
            for (int u = 0; u < 8; u++) q[u] = *(const unsigned int*)(Hl + e[u].x);
            #pragma unroll
            for (int u = 0; u < 8; u++) {
                float w = __uint_as_float(head ? e[u].z : e[u].y);
                f32x2 l, h; fp8_dec4v(q[u], l, h);
                den += w;
                f32x2 wv = {w, w};
                n01 += l * wv;
                n23 += h * wv;
            }
        }
        for (; i + 4 <= m; i += 4) {
            uint4 e[4];
            #pragma unroll
            for (int u = 0; u < 4; u++) e[u] = lw[wid][i + u];
            unsigned q[4];
            #pragma unroll
            for (int u = 0; u < 4; u++) q[u] = *(const unsigned int*)(Hl + e[u].x);
            #pragma unroll
            for (int u = 0; u < 4; u++) {
                float w = __uint_as_float(head ? e[u].z : e[u].y);
                f32x2 l, h; fp8_dec4v(q[u], l, h);
                den += w;
                f32x2 wv = {w, w};
                n01 += l * wv;
                n23 += h * wv;
            }
        }
        for (; i < m; i++) {
            uint4 e0 = lw[wid][i];
            unsigned q0 = *(const unsigned int*)(Hl + e0.x);
            float w = __uint_as_float(head ? e0.z : e0.y);
            f32x2 l, h; fp8_dec4v(q0, l, h);
            den += w;
            f32x2 wv = {w, w};
            n01 += l * wv;
            n23 += h * wv;
        }
    }
    float inv = 1.f / den;
    float v0 = n01[0] * inv, v1 = n01[1] * inv, v2 = n23[0] * inv, v3 = n23[1] * inv;
    float o0 = 0.5f * (v0 + __shfl_xor(v0, 32));
    float o1 = 0.5f * (v1 + __shfl_xor(v1, 32));
    float o2 = 0.5f * (v2 + __shfl_xor(v2, 32));
    float o3 = 0.5f * (v3 + __shfl_xor(v3, 32));
    if (lane < 32) {
        int c = lane * 4;
        float4 bv = *(const float4*)(bias + c);
        o0 = sigmoidf_(o0 + bv.x);
        o1 = sigmoidf_(o1 + bv.y);
        o2 = sigmoidf_(o2 + bv.z);
        o3 = sigmoidf_(o3 + bv.w);
        uint2 pv;
        pv.x = (unsigned int)f2bf(o0) | ((unsigned int)f2bf(o1) << 16);
        pv.y = (unsigned int)f2bf(o2) | ((unsigned int)f2bf(o3) << 16);
        *(uint2*)(Out + (size_t)node * 128 + c) = pv;
    }
}

// ---------------- gate logits via MFMA: M=64 tile, swizzled LDS ----------------
__global__ __launch_bounds__(256, 2) void k_gatemm(
    const unsigned short* __restrict__ Obuf,
    const unsigned short* __restrict__ GWT,
    const float* __restrict__ gb1p, const float* __restrict__ gw2f,
    const float* __restrict__ gb2f, float* __restrict__ logits)
{
    __shared__ __align__(16) unsigned short As[64 * 32];
    __shared__ __align__(16) unsigned short Bs[128 * 32];
    int tid = threadIdx.x;
    int wave = tid >> 6, lane = tid & 63;
    int quad = lane >> 4, lr = lane & 15;
    int m0 = blockIdx.x * 64;

    f32x4 zero4 = {0.f, 0.f, 0.f, 0.f};
    f32x4 acc[8];
    #pragma unroll
    for (int j = 0; j < 8; j++) acc[j] = zero4;

    for (int k0 = 0; k0 < 128; k0 += 32) {
        {
            int row = tid >> 2, part = tid & 3;
            int gr = m0 + row; if (gr >= NN) gr = NN - 1;
            int g = ((row >> 4) << 6) + (part << 4) + (row & 15);
            g ^= (part << 1);
            *(uint4*)(&As[g * 8]) =
                *(const uint4*)(Obuf + (size_t)gr * 128 + k0 + part * 8);
        }
        #pragma unroll
        for (int i = 0; i < 2; i++) {
            int idx = tid + i * 256;
            int row = idx >> 2, part = idx & 3;
            int g = ((row >> 4) << 6) + (part << 4) + (row & 15);
            g ^= (part << 1);
            *(uint4*)(&Bs[g * 8]) =
                *(const uint4*)(GWT + (size_t)row * 128 + k0 + part * 8);
        }
        __syncthreads();

        int sw = (quad << 1);
        bf16x8 af0 = *(const bf16x8*)(&As[((wave * 64 + lane) ^ sw) * 8]);
        #pragma unroll
        for (int ni = 0; ni < 8; ni++) {
            bf16x8 bfv = *(const bf16x8*)(&Bs[((ni * 64 + lane) ^ sw) * 8]);
            acc[ni] = __builtin_amdgcn_mfma_f32_16x16x32_bf16(af0, bfv, acc[ni], 0, 0, 0);
        }
        __syncthreads();
    }

    float gb[8], gw[8];
    #pragma unroll
    for (int ni = 0; ni < 8; ni++) { gb[ni] = gb1p[ni * 16 + lr]; gw[ni] = gw2f[ni * 16 + lr]; }
    #pragma unroll
    for (int r = 0; r < 4; r++) {
        int grow = m0 + wave * 16 + quad * 4 + r;
        float part = 0.f;
        #pragma unroll
        for (int ni = 0; ni < 8; ni++) {
            float v = acc[ni][r] + gb[ni];
            v = v > 0.f ? v : 0.f;
            part += v * gw[ni];
        }
        #pragma unroll
        for (int m = 1; m < 16; m <<= 1) part += __shfl_xor(part, m);
        if (lr == 0 && grow < NN) logits[grow] = part + gb2f[0];
    }
}

// ---------------- pooling ----------------
__device__ int lbound(const int* a, int n, int key) {
    int lo = 0, hi = n;
    while (lo < hi) { int mid = (lo + hi) >> 1; if (a[mid] < key) lo = mid + 1; else hi = mid; }
    return lo;
}

__global__ __launch_bounds__(256) void k_gmax(const float* __restrict__ logits,
                                              const int* __restrict__ batch,
                                              float* __restrict__ gmax) {
    __shared__ int sb[2];
    __shared__ float sm[256];
    int g = blockIdx.x, t = threadIdx.x;
    if (t < 2) sb[t] = lbound(batch, NN, g + t);
    __syncthreads();
    int lo = sb[0], hi = sb[1];
    float mx = -1e30f;
    for (int i = lo + t; i < hi; i += 256) mx = fmaxf(mx, logits[i]);
    sm[t] = mx; __syncthreads();
    for (int s = 128; s > 0; s >>= 1) { if (t < s) sm[t] = fmaxf(sm[t], sm[t + s]); __syncthreads(); }
    if (t == 0) gmax[g] = sm[0];
}

#define NPB 256
__global__ __launch_bounds__(256) void k_ppart(const unsigned short* __restrict__ Out2,
                                               const float* __restrict__ logits,
                                               const int* __restrict__ batch,
                                               const float* __restrict__ gmax,
                                               float* __restrict__ accv,
                                               float* __restrict__ accw) {
    int t = threadIdx.x;
    int c = t & 127, half = t >> 7;
    int b0 = blockIdx.x * NPB;
    int b1 = b0 + NPB; if (b1 > NN) b1 = NN;
    float acc = 0.f, aw = 0.f;
    int g = -1;
    for (int i = b0 + half; i < b1; i += 2) {
        int gi = batch[i];
        if (gi != g) {
            if (g >= 0) {
                atomicAdd(&accv[g * 128 + c], acc);
                if (c == 0) atomicAdd(&accw[g], aw);
            }
            g = gi; acc = 0.f; aw = 0.f;
        }
        float w = __expf(logits[i] - gmax[gi]);
        acc += w * bf2f(Out2[(size_t)i * 128 + c]);
        if (c == 0) aw += w;
    }
    if (g >= 0) {
        atomicAdd(&accv[g * 128 + c], acc);
        if (c == 0) atomicAdd(&accw[g], aw);
    }
}

__global__ __launch_bounds__(128) void k_pfin(const float* __restrict__ accv,
                                              const float* __restrict__ accw,
                                              const float* __restrict__ glwf,
                                              const float* __restrict__ glbf,
                                              const int* __restrict__ fflag,
                                              void* __restrict__ out) {
    __shared__ float sv[128];
    int g = blockIdx.x, t = threadIdx.x;
    float pooled = accv[g * 128 + t] / (accw[g] + 1e-16f);
    sv[t] = pooled * glwf[t];
    __syncthreads();
    for (int s = 64; s > 0; s >>= 1) { if (t < s) sv[t] += sv[t + s]; __syncthreads(); }
    if (t == 0) {
        float r = sigmoidf_(sv[0] + glbf[0]);
        if (fflag[0]) ((float*)out)[g] = r;
        else ((unsigned short*)out)[g] = f2bf(r);
    }
}

extern "C" void kernel_launch(void* const* d_in, const int* in_sizes, int n_in,
                              void* d_out, int out_size, void* d_ws, size_t ws_size,
                              hipStream_t stream) {
    const int* x_raw  = (const int*)d_in[0];
    const int* ei_raw = (const int*)d_in[1];
    const int* b_raw  = (const int*)d_in[3];

    char* p = (char*)d_ws;
    auto alloc = [&](size_t bytes) { void* r = (void*)p; p += (bytes + 255) & ~(size_t)255; return r; };
    unsigned char* H8   = (unsigned char*)alloc((size_t)NN * 256);
    unsigned short* Obuf = (unsigned short*)alloc((size_t)NN * 128 * 2);
    float* alS   = (float*)alloc((size_t)NN * 2 * 4);
    float* alD   = (float*)alloc((size_t)NN * 2 * 4);
    float* logit = (float*)alloc((size_t)NN * 4);
    char* z0 = p;
    int* count   = (int*)alloc((size_t)NN * 4);
    float* accv  = (float*)alloc(GG * 128 * 4);
    float* accw  = (float*)alloc(GG * 4);
    size_t zlen = (size_t)(p - z0);
    int* offs    = (int*)alloc((size_t)NN * 4);
    int* cursor  = (int*)alloc((size_t)NN * 4);
    int* sorted  = (int*)alloc((size_t)EE * 4);
    int* csum    = (int*)alloc(256 * 4);
    int* coff    = (int*)alloc(256 * 4);
    unsigned short* W2T  = (unsigned short*)alloc(256 * 128 * 2);
    unsigned short* GWT  = (unsigned short*)alloc(128 * 128 * 2);
    float* gb1p = (float*)alloc(128 * 4);
    float* Ptab = (float*)alloc(50 * 256 * 4);
    int* xn     = (int*)alloc((size_t)NN * 6 * 4);
    int* srcn   = (int*)alloc((size_t)EE * 4);
    int* dstn   = (int*)alloc((size_t)EE * 4);
    int* batchn = (int*)alloc((size_t)NN * 4);
    int* iflag  = (int*)alloc(256);
    int* fflag  = (int*)alloc(256);
    float* vs1  = (float*)alloc(256 * 4);
    float* vd1  = (float*)alloc(256 * 4);
    float* vs2  = (float*)alloc(256 * 4);
    float* vd2  = (float*)alloc(256 * 4);
    float* vb1  = (float*)alloc(128 * 4);
    float* vb2  = (float*)alloc(128 * 4);
    float* gw2f = (float*)alloc(128 * 4);
    float* glwf = (float*)alloc(128 * 4);
    float* gb2f = (float*)alloc(4);
    float* glbf = (float*)alloc(4);
    float* gmax = (float*)alloc(GG * 4);

    const int NCHUNK = (NN + 1023) / 1024;
    const int NBM = (NN + 63) / 64;
    const int NBE = (EE + 255) / 256;
    const int NB4 = (NN + 3) / 4;
    const int CVT_TOT = NN * 6 + 2 * EE + NN;

    hipMemsetAsync(z0, 0, zlen, stream);

    k_probe2<<<2, 256, 0, stream>>>((const unsigned int*)d_in[10], ei_raw, fflag, iflag);
    k_cvt<<<(CVT_TOT + 255) / 256, 256, 0, stream>>>(x_raw, ei_raw, b_raw, iflag,
                                                     xn, srcn, dstn, batchn, count);
    k_cvtp<<<(32768 + 255) / 256, 256, 0, stream>>>(
        d_in[14],
        d_in[11], d_in[12], d_in[13], d_in[15], d_in[16], d_in[17],
        d_in[18], d_in[19], d_in[20], d_in[21], d_in[22], d_in[23],
        d_in[24], d_in[25], d_in[26], d_in[27],
        fflag, W2T, GWT, gb1p,
        vs1, vd1, vs2, vd2, vb1, vb2, gw2f, glwf, gb2f, glbf);
    k_prep_p<<<50, 256, 0, stream>>>(d_in[4], d_in[5], d_in[6], d_in[7], d_in[8], d_in[9],
                                     d_in[10], fflag, Ptab);

    k_chunk_sum<<<NCHUNK, 256, 0, stream>>>(count, csum);
    k_chunk_scan<<<1, 256, 0, stream>>>(csum, coff, NCHUNK);
    k_scan_write<<<NCHUNK, 256, 0, stream>>>(count, coff, offs, cursor);
    k_scatter<<<NBE, 256, 0, stream>>>(srcn, dstn, cursor, sorted);

    // layer 1: P-table gather-sum (replaces K=384 GEMM)
    k_embsum<<<NB4, 256, 0, stream>>>(xn, Ptab, vs1, vd1, H8, alS, alD);
    k_agg<<<NB4, 256, 0, stream>>>(H8, alS, alD, sorted, offs, count, vb1, Obuf);

    // layer 2
    k_gemm<<<NBM, 256, 0, stream>>>(Obuf, W2T, H8, vs2, vd2, alS, alD, 128);
    k_agg<<<NB4, 256, 0, stream>>>(H8, alS, alD, sorted, offs, count, vb2, Obuf);

    // pooling head
    k_gatemm<<<NBM, 256, 0, stream>>>(Obuf, GWT, gb1p, gw2f, gb2f, logit);
    k_gmax<<<GG, 256, 0, stream>>>(logit, batchn, gmax);
    k_ppart<<<(NN + NPB - 1) / NPB, 256, 0, stream>>>(Obuf, logit, batchn, gmax, accv, accw);
    k_pfin<<<GG, 128, 0, stream>>>(accv, accw, glwf, glbf, fflag, d_out);
}

// Round 14
// 413.291 us; speedup vs baseline: 1.1084x; 1.1084x over previous
//
#include <hip/hip_runtime.h>
#include <hip/hip_bf16.h>
#include <hip/hip_fp16.h>

#define NN 100000
#define EE 800000
#define GG 128

typedef short bf16x8 __attribute__((ext_vector_type(8)));
typedef float f32x4 __attribute__((ext_vector_type(4)));
typedef float f32x2 __attribute__((ext_vector_type(2)));

__device__ __forceinline__ float bf2f(unsigned short v) {
    union { unsigned int u; float f; } x; x.u = ((unsigned int)v) << 16; return x.f;
}
__device__ __forceinline__ unsigned short f2bf(float f) {
    union { float f; unsigned int u; } x; x.f = f;
    unsigned int r = x.u + 0x7fffu + ((x.u >> 16) & 1u);
    return (unsigned short)(r >> 16);
}
__device__ __forceinline__ float sigmoidf_(float x) { return 1.f / (1.f + __expf(-x)); }
__device__ __forceinline__ float ldp(const void* p, int i, int f) {
    return f ? ((const float*)p)[i] : bf2f(((const unsigned short*)p)[i]);
}

// ---------------- fp8 helpers ----------------
#if defined(__has_builtin)
#if __has_builtin(__builtin_amdgcn_cvt_pk_f32_fp8) && __has_builtin(__builtin_amdgcn_cvt_pk_fp8_f32)
#define USE_HW_FP8 1
#endif
#endif
#ifndef USE_HW_FP8
#define USE_HW_FP8 0
#endif

#if USE_HW_FP8
__device__ __forceinline__ int fp8_pack2(float a, float b) {
    return __builtin_amdgcn_cvt_pk_fp8_f32(a, b, 0, false);
}
__device__ __forceinline__ void fp8_dec4v(unsigned int q, f32x2& lo, f32x2& hi) {
    lo = __builtin_amdgcn_cvt_pk_f32_fp8((int)q, false);
    hi = __builtin_amdgcn_cvt_pk_f32_fp8((int)q, true);
}
#else
__device__ __forceinline__ unsigned char f2bf8(float f) {
    unsigned short u = __half_as_ushort(__float2half(f));
    unsigned short r = u + 0x7f + ((u >> 8) & 1);
    return (unsigned char)(r >> 8);
}
__device__ __forceinline__ int fp8_pack2(float a, float b) {
    return (int)f2bf8(a) | ((int)f2bf8(b) << 8);
}
__device__ __forceinline__ float bf8_dec(unsigned int b) {
    return __half2float(__ushort_as_half((unsigned short)(b << 8)));
}
__device__ __forceinline__ void fp8_dec4v(unsigned int q, f32x2& lo, f32x2& hi) {
    lo[0] = bf8_dec(q & 0xff); lo[1] = bf8_dec((q >> 8) & 0xff);
    hi[0] = bf8_dec((q >> 16) & 0xff); hi[1] = bf8_dec(q >> 24);
}
#endif

// ---------------- merged dtype probes ----------------
__global__ void k_probe2(const unsigned int* __restrict__ w, const int* __restrict__ ei,
                         int* __restrict__ fflag, int* __restrict__ iflag) {
    __shared__ int s[256];
    int t = threadIdx.x;
    if (blockIdx.x == 0) {
        int cnt = 0;
        for (int i = t; i < 1024; i += 256) {
            unsigned int v = w[i];
            int e = (v >> 7) & 0xff;
            cnt += (e >= 100 && e <= 127) ? 1 : 0;
        }
        s[t] = cnt; __syncthreads();
        for (int d = 128; d > 0; d >>= 1) { if (t < d) s[t] += s[t + d]; __syncthreads(); }
        if (t == 0) fflag[0] = (s[0] >= 512) ? 0 : 1;
    } else {
        int nz = 0;
        for (int i = t; i < 1024; i += 256) nz |= ei[2 * i + 1];
        s[t] = nz; __syncthreads();
        for (int d = 128; d > 0; d >>= 1) { if (t < d) s[t] |= s[t + d]; __syncthreads(); }
        if (t == 0) iflag[0] = (s[0] == 0) ? 1 : 0;   // 1 => int64 (shift by 1)
    }
}

// ---------------- histogram of dst (reads raw edge_index) ----------------
__global__ void k_hist(const int* __restrict__ ei, const int* __restrict__ iflag,
                       int* __restrict__ count) {
    int e = blockIdx.x * 256 + threadIdx.x;
    if (e < EE) {
        int f = iflag[0];
        int d = ei[(EE + e) << f];
        atomicAdd(&count[d], 1);
    }
}

// ---------------- counting sort ----------------
__global__ void k_chunk_sum(const int* __restrict__ count, int* __restrict__ csum) {
    __shared__ int s[256];
    int t = threadIdx.x;
    int base = blockIdx.x * 1024 + t * 4;
    int acc = 0;
    #pragma unroll
    for (int j = 0; j < 4; j++) { int n = base + j; if (n < NN) acc += count[n]; }
    s[t] = acc; __syncthreads();
    for (int d = 128; d > 0; d >>= 1) { if (t < d) s[t] += s[t + d]; __syncthreads(); }
    if (t == 0) csum[blockIdx.x] = s[0];
}

__global__ void k_chunk_scan(const int* __restrict__ csum, int* __restrict__ coff, int nchunk) {
    __shared__ int s[256];
    int t = threadIdx.x;
    int v = (t < nchunk) ? csum[t] : 0;
    s[t] = v; __syncthreads();
    for (int d = 1; d < 256; d <<= 1) {
        int x = (t >= d) ? s[t - d] : 0;
        __syncthreads(); s[t] += x; __syncthreads();
    }
    if (t < nchunk) coff[t] = s[t] - v;
}

__global__ void k_scan_write(const int* __restrict__ count, const int* __restrict__ coff,
                             int* __restrict__ offset, int* __restrict__ cursor) {
    __shared__ int s[256];
    int t = threadIdx.x;
    int base = blockIdx.x * 1024 + t * 4;
    int v[4]; int acc = 0;
    #pragma unroll
    for (int j = 0; j < 4; j++) { v[j] = (base + j < NN) ? count[base + j] : 0; acc += v[j]; }
    s[t] = acc; __syncthreads();
    for (int d = 1; d < 256; d <<= 1) {
        int x = (t >= d) ? s[t - d] : 0;
        __syncthreads(); s[t] += x; __syncthreads();
    }
    int pre = s[t] - acc + coff[blockIdx.x];
    #pragma unroll
    for (int j = 0; j < 4; j++) {
        if (base + j < NN) { offset[base + j] = pre; cursor[base + j] = pre; pre += v[j]; }
    }
}

__global__ void k_scatter(const int* __restrict__ ei, const int* __restrict__ iflag,
                          int* __restrict__ cursor, int* __restrict__ sorted) {
    int e = blockIdx.x * 256 + threadIdx.x;
    if (e < EE) {
        int f = iflag[0];
        int s = ei[e << f];
        int d = ei[(EE + e) << f];
        int p = atomicAdd(&cursor[d], 1);
        sorted[p] = s;
    }
}

// ---------------- merged param conversion + P-table ----------------
__constant__ int c_vbase[7] = {0, 33, 38, 41, 45, 47, 50};
__global__ __launch_bounds__(256) void k_prep(
    const void* e0, const void* e1, const void* e2,
    const void* e3, const void* e4, const void* e5,
    const void* W1, const void* W2,
    const void* as1, const void* ad1, const void* b1,
    const void* as2, const void* ad2, const void* b2,
    const void* gw1, const void* gb1,
    const void* bng, const void* bnb, const void* bnm, const void* bnv,
    const void* gw2, const void* gb2, const void* glw, const void* glb,
    const int* __restrict__ fflag,
    unsigned short* __restrict__ W2T,
    unsigned short* __restrict__ GWT, float* __restrict__ gb1p,
    float* __restrict__ vs1, float* __restrict__ vd1,
    float* __restrict__ vs2, float* __restrict__ vd2,
    float* __restrict__ vb1, float* __restrict__ vb2,
    float* __restrict__ gw2f, float* __restrict__ glwf,
    float* __restrict__ gb2f, float* __restrict__ glbf,
    float* __restrict__ P) {
    int f = fflag[0];
    if (blockIdx.x >= 128) {
        // P-table rows
        int r = blockIdx.x - 128;    // 0..49
        int c = threadIdx.x;
        int t = 0;
        while (r >= c_vbase[t + 1]) t++;
        int v = r - c_vbase[t];
        const void* emb = (t == 0) ? e0 : (t == 1) ? e1 : (t == 2) ? e2 :
                          (t == 3) ? e3 : (t == 4) ? e4 : e5;
        float acc = 0.f;
        #pragma unroll 8
        for (int k = 0; k < 64; k++) {
            acc += ldp(emb, v * 64 + k, f) * ldp(W1, (t * 64 + k) * 256 + c, f);
        }
        P[r * 256 + c] = acc;
        return;
    }
    int i = blockIdx.x * 256 + threadIdx.x;
    if (i < 32768) { int k = i / 256, n = i % 256; W2T[n * 128 + k] = f2bf(ldp(W2, i, f)); }
    if (i < 16384) {
        int n = i >> 7, k = i & 127;
        float sc = ldp(bng, n, f) * rsqrtf(ldp(bnv, n, f) + 1e-5f);
        GWT[i] = f2bf(ldp(gw1, k * 128 + n, f) * sc);
    }
    if (i < 256) {
        vs1[i] = ldp(as1, i, f); vd1[i] = ldp(ad1, i, f);
        vs2[i] = ldp(as2, i, f); vd2[i] = ldp(ad2, i, f);
    }
    if (i < 128) {
        vb1[i] = ldp(b1, i, f); vb2[i] = ldp(b2, i, f);
        gw2f[i] = ldp(gw2, i, f); glwf[i] = ldp(glw, i, f);
        float sc = ldp(bng, i, f) * rsqrtf(ldp(bnv, i, f) + 1e-5f);
        gb1p[i] = (ldp(gb1, i, f) - ldp(bnm, i, f)) * sc + ldp(bnb, i, f);
    }
    if (i == 0) { gb2f[0] = ldp(gb2, 0, f); glbf[0] = ldp(glb, 0, f); }
}

// ---------------- layer-1: H = sum_t P[x_t] + fused al + fp8 store (raw x) ----------------
__global__ __launch_bounds__(256) void k_embsum(
    const int* __restrict__ x_raw, const int* __restrict__ iflag,
    const float* __restrict__ P,
    const float* __restrict__ avs, const float* __restrict__ avd,
    unsigned char* __restrict__ H8,
    float* __restrict__ alS, float* __restrict__ alD) {
    int node = blockIdx.x * 4 + (threadIdx.x >> 6);
    if (node >= NN) return;
    int f = iflag[0];
    int lane = threadIdx.x & 63;
    int c0 = lane * 4;
    int ix[6];
    #pragma unroll
    for (int t = 0; t < 6; t++) ix[t] = (c_vbase[t] + x_raw[(node * 6 + t) << f]) * 256 + c0;
    float4 a = *(const float4*)(P + ix[0]);
    #pragma unroll
    for (int t = 1; t < 6; t++) {
        float4 b = *(const float4*)(P + ix[t]);
        a.x += b.x; a.y += b.y; a.z += b.z; a.w += b.w;
    }
    float4 sv = *(const float4*)(avs + c0);
    float4 dv = *(const float4*)(avd + c0);
    float ps = a.x * sv.x + a.y * sv.y + a.z * sv.z + a.w * sv.w;
    float pd = a.x * dv.x + a.y * dv.y + a.z * dv.z + a.w * dv.w;
    #pragma unroll
    for (int m = 1; m < 32; m <<= 1) {
        ps += __shfl_xor(ps, m);
        pd += __shfl_xor(pd, m);
    }
    if ((lane & 31) == 0) {
        int head = lane >> 5;
        alS[node * 2 + head] = ps;
        alD[node * 2 + head] = pd;
    }
    unsigned int u = ((unsigned)fp8_pack2(a.x, a.y) & 0xffffu) |
                     ((unsigned)fp8_pack2(a.z, a.w) << 16);
    *(unsigned int*)(H8 + (size_t)node * 256 + c0) = u;
}

// ---------------- MFMA GEMM (layer 2): M=64 tile, swizzled LDS ----------------
__global__ __launch_bounds__(256, 2) void k_gemm(
    const unsigned short* __restrict__ Ain,
    const unsigned short* __restrict__ WT, unsigned char* __restrict__ H8,
    const float* __restrict__ avs, const float* __restrict__ avd,
    float* __restrict__ alS, float* __restrict__ alD,
    int K)
{
    __shared__ __align__(16) unsigned short As[64 * 32];
    __shared__ __align__(16) unsigned short Bs[256 * 32];
    int tid = threadIdx.x;
    int wave = tid >> 6, lane = tid & 63;
    int quad = lane >> 4, lr = lane & 15;
    int m0 = blockIdx.x * 64;

    f32x4 zero4 = {0.f, 0.f, 0.f, 0.f};
    f32x4 acc[16];
    #pragma unroll
    for (int j = 0; j < 16; j++) acc[j] = zero4;

    for (int k0 = 0; k0 < K; k0 += 32) {
        {
            int row = tid >> 2, part = tid & 3;
            int gr = m0 + row; if (gr >= NN) gr = NN - 1;
            int g = ((row >> 4) << 6) + (part << 4) + (row & 15);
            g ^= (part << 1);
            *(uint4*)(&As[g * 8]) = *(const uint4*)(Ain + (size_t)gr * K + k0 + part * 8);
        }
        #pragma unroll
        for (int i = 0; i < 4; i++) {
            int idx = tid + i * 256;
            int row = idx >> 2, part = idx & 3;
            int g = ((row >> 4) << 6) + (part << 4) + (row & 15);
            g ^= (part << 1);
            *(uint4*)(&Bs[g * 8]) =
                *(const uint4*)(WT + (size_t)row * K + k0 + part * 8);
        }
        __syncthreads();

        int sw = (quad << 1);
        bf16x8 af0 = *(const bf16x8*)(&As[((wave * 64 + lane) ^ sw) * 8]);
        #pragma unroll
        for (int ni = 0; ni < 16; ni++) {
            bf16x8 bfv = *(const bf16x8*)(&Bs[((ni * 64 + lane) ^ sw) * 8]);
            acc[ni] = __builtin_amdgcn_mfma_f32_16x16x32_bf16(af0, bfv, acc[ni], 0, 0, 0);
        }
        __syncthreads();
    }

    float svv[16], dvv[16];
    #pragma unroll
    for (int ni = 0; ni < 16; ni++) { svv[ni] = avs[ni * 16 + lr]; dvv[ni] = avd[ni * 16 + lr]; }
    #pragma unroll
    for (int r = 0; r < 4; r++) {
        int grow = m0 + wave * 16 + quad * 4 + r;
        float ps0 = 0.f, ps1 = 0.f, pd0 = 0.f, pd1 = 0.f;
        if (grow < NN) {
            #pragma unroll
            for (int ni = 0; ni < 16; ni += 2) {
                float v0 = acc[ni][r], v1 = acc[ni + 1][r];
                int pk = fp8_pack2(v0, v1);
                H8[(size_t)grow * 256 + ni * 16 + lr] = (unsigned char)(pk & 0xff);
                H8[(size_t)grow * 256 + (ni + 1) * 16 + lr] = (unsigned char)((pk >> 8) & 0xff);
                if (ni < 8) { ps0 += v0 * svv[ni] + v1 * svv[ni + 1]; pd0 += v0 * dvv[ni] + v1 * dvv[ni + 1]; }
                else        { ps1 += v0 * svv[ni] + v1 * svv[ni + 1]; pd1 += v0 * dvv[ni] + v1 * dvv[ni + 1]; }
            }
        }
        #pragma unroll
        for (int m = 1; m < 16; m <<= 1) {
            ps0 += __shfl_xor(ps0, m); ps1 += __shfl_xor(ps1, m);
            pd0 += __shfl_xor(pd0, m); pd1 += __shfl_xor(pd1, m);
        }
        if (lr == 0 && grow < NN) {
            alS[grow * 2 + 0] = ps0; alS[grow * 2 + 1] = ps1;
            alD[grow * 2 + 0] = pd0; alD[grow * 2 + 1] = pd1;
        }
    }
}

// ---------------- fused edge-weight + segment aggregation ----------------
__device__ __forceinline__ float edge_w(float e) {
    e = e > 0.f ? e : 0.2f * e;
    e = fminf(fmaxf(e, -60.f), 60.f);
    return __expf(e);
}
__global__ __launch_bounds__(256) void k_agg(const unsigned char* __restrict__ H8,
                                             const float* __restrict__ alS, const float* __restrict__ alD,
                                             const int* __restrict__ sorted, const int* __restrict__ offs,
                                             const int* __restrict__ cnts,
                                             const float* __restrict__ bias,
                                             unsigned short* __restrict__ Out) {
    __shared__ uint4 lw[4][64];
    int wid = threadIdx.x >> 6;
    int node = blockIdx.x * 4 + wid;
    if (node >= NN) return;
    int lane = threadIdx.x & 63;
    int head = lane >> 5;
    float2 adv = *(const float2*)(alD + node * 2);
    float myAd = head ? adv.y : adv.x;
    const unsigned char* Hl = H8 + lane * 4;

    float ws = edge_w(alS[node * 2 + head] + myAd);
    unsigned int qv = *(const unsigned int*)(Hl + ((unsigned)node << 8));
    f32x2 lo, hi; fp8_dec4v(qv, lo, hi);
    float den = ws;
    f32x2 wsv = {ws, ws};
    f32x2 n01 = lo * wsv, n23 = hi * wsv;

    int off = offs[node], cnt = cnts[node];
    for (int c = 0; c < cnt; c += 64) {
        int m = cnt - c; if (m > 64) m = 64;
        int j = off + c + (lane < m ? lane : 0);
        int s = sorted[j];
        float2 asv = *(const float2*)(alS + s * 2);
        float w0 = edge_w(asv.x + adv.x);
        float w1 = edge_w(asv.y + adv.y);
        lw[wid][lane] = make_uint4((unsigned)s << 8, __float_as_uint(w0), __float_as_uint(w1), 0u);
        int i = 0;
        for (; i + 8 <= m; i += 8) {
            uint4 e[8];
            #pragma unroll
            for (int u = 0; u < 8; u++) e[u] = lw[wid][i + u];
            unsigned q[8];
            #pragma unroll
            for (int u = 0; u < 8; u++) q[u] = *(const unsigned int*)(Hl + e[u].x);
            #pragma unroll
            for (int u = 0; u < 8; u++) {
                float w = __uint_as_float(head ? e[u].z : e[u].y);
                f32x2 l, h; fp8_dec4v(q[u], l, h);
                den += w;
                f32x2 wv = {w, w};
                n01 += l * wv;
                n23 += h * wv;
            }
        }
        for (; i + 4 <= m; i += 4) {
            uint4 e[4];
            #pragma unroll
            for (int u = 0; u < 4; u++) e[u] = lw[wid][i + u];
            unsigned q[4];
            #pragma unroll
            for (int u = 0; u < 4; u++) q[u] = *(const unsigned int*)(Hl + e[u].x);
            #pragma unroll
            for (int u = 0; u < 4; u++) {
                float w = __uint_as_float(head ? e[u].z : e[u].y);
                f32x2 l, h; fp8_dec4v(q[u], l, h);
                den += w;
                f32x2 wv = {w, w};
                n01 += l * wv;
                n23 += h * wv;
            }
        }
        for (; i < m; i++) {
            uint4 e0 = lw[wid][i];
            unsigned q0 = *(const unsigned int*)(Hl + e0.x);
            float w = __uint_as_float(head ? e0.z : e0.y);
            f32x2 l, h; fp8_dec4v(q0, l, h);
            den += w;
            f32x2 wv = {w, w};
            n01 += l * wv;
            n23 += h * wv;
        }
    }
    float inv = 1.f / den;
    float v0 = n01[0] * inv, v1 = n01[1] * inv, v2 = n23[0] * inv, v3 = n23[1] * inv;
    float o0 = 0.5f * (v0 + __shfl_xor(v0, 32));
    float o1 = 0.5f * (v1 + __shfl_xor(v1, 32));
    float o2 = 0.5f * (v2 + __shfl_xor(v2, 32));
    float o3 = 0.5f * (v3 + __shfl_xor(v3, 32));
    if (lane < 32) {
        int c = lane * 4;
        float4 bv = *(const float4*)(bias + c);
        o0 = sigmoidf_(o0 + bv.x);
        o1 = sigmoidf_(o1 + bv.y);
        o2 = sigmoidf_(o2 + bv.z);
        o3 = sigmoidf_(o3 + bv.w);
        uint2 pv;
        pv.x = (unsigned int)f2bf(o0) | ((unsigned int)f2bf(o1) << 16);
        pv.y = (unsigned int)f2bf(o2) | ((unsigned int)f2bf(o3) << 16);
        *(uint2*)(Out + (size_t)node * 128 + c) = pv;
    }
}

// ---------------- fused gate+pool: whole-tile MFMA -> logits -> per-graph accumulate ----------------
// LDS granule (row, p), p in 0..15 (16B each): slot = row*16 + (p&8) + ((p&7)^(row&7)).
__global__ __launch_bounds__(256, 2) void k_gate(
    const unsigned short* __restrict__ Obuf,
    const unsigned short* __restrict__ GWT,
    const float* __restrict__ gb1p, const float* __restrict__ gw2f,
    const float* __restrict__ gb2f,
    const int* __restrict__ batch_raw, const int* __restrict__ iflag,
    float* __restrict__ accv, float* __restrict__ accw)
{
    __shared__ __align__(16) unsigned short As[64 * 128];
    __shared__ __align__(16) unsigned short Bs[128 * 128];
    __shared__ float wlds[64];
    __shared__ int gid[64];
    int tid = threadIdx.x;
    int wave = tid >> 6, lane = tid & 63;
    int quad = lane >> 4, lr = lane & 15;
    int m0 = blockIdx.x * 64;

    // stage full A (64x128) and B (128x128)
    #pragma unroll
    for (int i = 0; i < 4; i++) {
        int idx = tid + i * 256;                // 0..1023
        int row = idx >> 4, p = idx & 15;
        int gr = m0 + row; if (gr >= NN) gr = NN - 1;
        int slot = row * 16 + (p & 8) + ((p & 7) ^ (row & 7));
        *(uint4*)(&As[slot * 8]) = *(const uint4*)(Obuf + (size_t)gr * 128 + p * 8);
    }
    #pragma unroll
    for (int i = 0; i < 8; i++) {
        int idx = tid + i * 256;                // 0..2047
        int row = idx >> 4, p = idx & 15;
        int slot = row * 16 + (p & 8) + ((p & 7) ^ (row & 7));
        *(uint4*)(&Bs[slot * 8]) = *(const uint4*)(GWT + (size_t)row * 128 + p * 8);
    }
    if (tid < 64) {
        int nd = m0 + tid; if (nd >= NN) nd = NN - 1;
        gid[tid] = batch_raw[nd << iflag[0]];
    }
    __syncthreads();

    f32x4 zero4 = {0.f, 0.f, 0.f, 0.f};
    f32x4 acc[8];
    #pragma unroll
    for (int j = 0; j < 8; j++) acc[j] = zero4;

    int rowa = wave * 16 + lr;
    #pragma unroll
    for (int k0 = 0; k0 < 128; k0 += 32) {
        int kb = k0 >> 3;                        // 0,4,8,12
        int pa = (kb & 8) + (((kb & 7) + quad) ^ (lr & 7));
        bf16x8 af0 = *(const bf16x8*)(&As[(rowa * 16 + pa) * 8]);
        #pragma unroll
        for (int ni = 0; ni < 8; ni++) {
            int rowb = ni * 16 + lr;
            bf16x8 bfv = *(const bf16x8*)(&Bs[(rowb * 16 + pa) * 8]);
            acc[ni] = __builtin_amdgcn_mfma_f32_16x16x32_bf16(af0, bfv, acc[ni], 0, 0, 0);
        }
    }

    // logits -> w per row (no max-subtract: |logit| small)
    float gb[8], gw[8];
    #pragma unroll
    for (int ni = 0; ni < 8; ni++) { gb[ni] = gb1p[ni * 16 + lr]; gw[ni] = gw2f[ni * 16 + lr]; }
    #pragma unroll
    for (int r = 0; r < 4; r++) {
        int row = wave * 16 + quad * 4 + r;
        float part = 0.f;
        #pragma unroll
        for (int ni = 0; ni < 8; ni++) {
            float v = acc[ni][r] + gb[ni];
            v = v > 0.f ? v : 0.f;
            part += v * gw[ni];
        }
        #pragma unroll
        for (int m = 1; m < 16; m <<= 1) part += __shfl_xor(part, m);
        if (lr == 0) {
            float w = (m0 + row < NN) ? __expf(part + gb2f[0]) : 0.f;
            wlds[row] = w;
        }
    }
    __syncthreads();

    // per-graph accumulation from LDS A-tile: thread t handles ch = t&127, rows (t>>7)*32..+32
    int ch = tid & 127;
    int r0 = (tid >> 7) * 32;
    int p = ch >> 3, ip = ch & 7;
    float accum = 0.f, aw = 0.f;
    int g = -1;
    for (int rr = 0; rr < 32; rr++) {
        int row = r0 + rr;
        int gi = gid[row];
        float w = wlds[row];
        if (gi != g) {
            if (g >= 0) {
                atomicAdd(&accv[g * 128 + ch], accum);
                if (ch == 0) atomicAdd(&accw[g], aw);
            }
            g = gi; accum = 0.f; aw = 0.f;
        }
        int slot = row * 16 + (p & 8) + ((p & 7) ^ (row & 7));
        float val = bf2f(As[slot * 8 + ip]);
        accum += w * val;
        if (ch == 0) aw += w;
    }
    if (g >= 0) {
        atomicAdd(&accv[g * 128 + ch], accum);
        if (ch == 0) atomicAdd(&accw[g], aw);
    }
}

// ---------------- final head ----------------
__global__ __launch_bounds__(128) void k_pfin(const float* __restrict__ accv,
                                              const float* __restrict__ accw,
                                              const float* __restrict__ glwf,
                                              const float* __restrict__ glbf,
                                              const int* __restrict__ fflag,
                                              void* __restrict__ out) {
    __shared__ float sv[128];
    int g = blockIdx.x, t = threadIdx.x;
    float pooled = accv[g * 128 + t] / (accw[g] + 1e-16f);
    sv[t] = pooled * glwf[t];
    __syncthreads();
    for (int s = 64; s > 0; s >>= 1) { if (t < s) sv[t] += sv[t + s]; __syncthreads(); }
    if (t == 0) {
        float r = sigmoidf_(sv[0] + glbf[0]);
        if (fflag[0]) ((float*)out)[g] = r;
        else ((unsigned short*)out)[g] = f2bf(r);
    }
}

extern "C" void kernel_launch(void* const* d_in, const int* in_sizes, int n_in,
                              void* d_out, int out_size, void* d_ws, size_t ws_size,
                              hipStream_t stream) {
    const int* x_raw  = (const int*)d_in[0];
    const int* ei_raw = (const int*)d_in[1];
    const int* b_raw  = (const int*)d_in[3];

    char* p = (char*)d_ws;
    auto alloc = [&](size_t bytes) { void* r = (void*)p; p += (bytes + 255) & ~(size_t)255; return r; };
    unsigned char* H8   = (unsigned char*)alloc((size_t)NN * 256);
    unsigned short* Obuf = (unsigned short*)alloc((size_t)NN * 128 * 2);
    float* alS   = (float*)alloc((size_t)NN * 2 * 4);
    float* alD   = (float*)alloc((size_t)NN * 2 * 4);
    char* z0 = p;
    int* count   = (int*)alloc((size_t)NN * 4);
    float* accv  = (float*)alloc(GG * 128 * 4);
    float* accw  = (float*)alloc(GG * 4);
    size_t zlen = (size_t)(p - z0);
    int* offs    = (int*)alloc((size_t)NN * 4);
    int* cursor  = (int*)alloc((size_t)NN * 4);
    int* sorted  = (int*)alloc((size_t)EE * 4);
    int* csum    = (int*)alloc(256 * 4);
    int* coff    = (int*)alloc(256 * 4);
    unsigned short* W2T  = (unsigned short*)alloc(256 * 128 * 2);
    unsigned short* GWT  = (unsigned short*)alloc(128 * 128 * 2);
    float* gb1p = (float*)alloc(128 * 4);
    float* Ptab = (float*)alloc(50 * 256 * 4);
    int* iflag  = (int*)alloc(256);
    int* fflag  = (int*)alloc(256);
    float* vs1  = (float*)alloc(256 * 4);
    float* vd1  = (float*)alloc(256 * 4);
    float* vs2  = (float*)alloc(256 * 4);
    float* vd2  = (float*)alloc(256 * 4);
    float* vb1  = (float*)alloc(128 * 4);
    float* vb2  = (float*)alloc(128 * 4);
    float* gw2f = (float*)alloc(128 * 4);
    float* glwf = (float*)alloc(128 * 4);
    float* gb2f = (float*)alloc(4);
    float* glbf = (float*)alloc(4);

    const int NCHUNK = (NN + 1023) / 1024;
    const int NBM = (NN + 63) / 64;
    const int NBE = (EE + 255) / 256;
    const int NB4 = (NN + 3) / 4;

    hipMemsetAsync(z0, 0, zlen, stream);

    k_probe2<<<2, 256, 0, stream>>>((const unsigned int*)d_in[10], ei_raw, fflag, iflag);
    k_hist<<<NBE, 256, 0, stream>>>(ei_raw, iflag, count);
    k_prep<<<178, 256, 0, stream>>>(
        d_in[4], d_in[5], d_in[6], d_in[7], d_in[8], d_in[9],
        d_in[10], d_in[14],
        d_in[11], d_in[12], d_in[13], d_in[15], d_in[16], d_in[17],
        d_in[18], d_in[19], d_in[20], d_in[21], d_in[22], d_in[23],
        d_in[24], d_in[25], d_in[26], d_in[27],
        fflag, W2T, GWT, gb1p,
        vs1, vd1, vs2, vd2, vb1, vb2, gw2f, glwf, gb2f, glbf, Ptab);

    k_chunk_sum<<<NCHUNK, 256, 0, stream>>>(count, csum);
    k_chunk_scan<<<1, 256, 0, stream>>>(csum, coff, NCHUNK);
    k_scan_write<<<NCHUNK, 256, 0, stream>>>(count, coff, offs, cursor);
    k_scatter<<<NBE, 256, 0, stream>>>(ei_raw, iflag, cursor, sorted);

    // layer 1
    k_embsum<<<NB4, 256, 0, stream>>>(x_raw, iflag, Ptab, vs1, vd1, H8, alS, alD);
    k_agg<<<NB4, 256, 0, stream>>>(H8, alS, alD, sorted, offs, count, vb1, Obuf);

    // layer 2
    k_gemm<<<NBM, 256, 0, stream>>>(Obuf, W2T, H8, vs2, vd2, alS, alD, 128);
    k_agg<<<NB4, 256, 0, stream>>>(H8, alS, alD, sorted, offs, count, vb2, Obuf);

    // fused pooling head
    k_gate<<<NBM, 256, 0, stream>>>(Obuf, GWT, gb1p, gw2f, gb2f, b_raw, iflag, accv, accw);
    k_pfin<<<GG, 128, 0, stream>>>(accv, accw, glwf, glbf, fflag, d_out);
}

// Round 15
// 405.163 us; speedup vs baseline: 1.1306x; 1.0201x over previous
//
#include <hip/hip_runtime.h>
#include <hip/hip_bf16.h>
#include <hip/hip_fp16.h>

#define NN 100000
#define EE 800000
#define GG 128
#define NBE 3125            // (EE+255)/256
#define NPREP 178           // 128 conv blocks + 50 P-table rows
#define NB4 25000           // (NN+3)/4

typedef short bf16x8 __attribute__((ext_vector_type(8)));
typedef float f32x4 __attribute__((ext_vector_type(4)));
typedef float f32x2 __attribute__((ext_vector_type(2)));

__device__ __forceinline__ float bf2f(unsigned short v) {
    union { unsigned int u; float f; } x; x.u = ((unsigned int)v) << 16; return x.f;
}
__device__ __forceinline__ unsigned short f2bf(float f) {
    union { float f; unsigned int u; } x; x.f = f;
    unsigned int r = x.u + 0x7fffu + ((x.u >> 16) & 1u);
    return (unsigned short)(r >> 16);
}
__device__ __forceinline__ float sigmoidf_(float x) { return 1.f / (1.f + __expf(-x)); }
__device__ __forceinline__ float ldp(const void* p, int i, int f) {
    return f ? ((const float*)p)[i] : bf2f(((const unsigned short*)p)[i]);
}

// ---------------- fp8 helpers ----------------
#if defined(__has_builtin)
#if __has_builtin(__builtin_amdgcn_cvt_pk_f32_fp8) && __has_builtin(__builtin_amdgcn_cvt_pk_fp8_f32)
#define USE_HW_FP8 1
#endif
#endif
#ifndef USE_HW_FP8
#define USE_HW_FP8 0
#endif

#if USE_HW_FP8
__device__ __forceinline__ int fp8_pack2(float a, float b) {
    return __builtin_amdgcn_cvt_pk_fp8_f32(a, b, 0, false);
}
__device__ __forceinline__ void fp8_dec4v(unsigned int q, f32x2& lo, f32x2& hi) {
    lo = __builtin_amdgcn_cvt_pk_f32_fp8((int)q, false);
    hi = __builtin_amdgcn_cvt_pk_f32_fp8((int)q, true);
}
#else
__device__ __forceinline__ unsigned char f2bf8(float f) {
    unsigned short u = __half_as_ushort(__float2half(f));
    unsigned short r = u + 0x7f + ((u >> 8) & 1);
    return (unsigned char)(r >> 8);
}
__device__ __forceinline__ int fp8_pack2(float a, float b) {
    return (int)f2bf8(a) | ((int)f2bf8(b) << 8);
}
__device__ __forceinline__ float bf8_dec(unsigned int b) {
    return __half2float(__ushort_as_half((unsigned short)(b << 8)));
}
__device__ __forceinline__ void fp8_dec4v(unsigned int q, f32x2& lo, f32x2& hi) {
    lo[0] = bf8_dec(q & 0xff); lo[1] = bf8_dec((q >> 8) & 0xff);
    hi[0] = bf8_dec((q >> 16) & 0xff); hi[1] = bf8_dec(q >> 24);
}
#endif

__constant__ int c_vbase[7] = {0, 33, 38, 41, 45, 47, 50};

// ---------------- front: hist (blocks 0..NBE-1) || prep (blocks NBE..NBE+NPREP-1) ----------------
__global__ __launch_bounds__(256) void k_front(
    const int* __restrict__ ei, int* __restrict__ count,
    int* __restrict__ iflag, int* __restrict__ fflag,
    const void* e0, const void* e1, const void* e2,
    const void* e3, const void* e4, const void* e5,
    const void* W1, const void* W2,
    const void* as1, const void* ad1, const void* b1,
    const void* as2, const void* ad2, const void* b2,
    const void* gw1, const void* gb1,
    const void* bng, const void* bnb, const void* bnm, const void* bnv,
    const void* gw2, const void* gb2, const void* glw, const void* glb,
    unsigned short* __restrict__ W2T,
    unsigned short* __restrict__ GWT, float* __restrict__ gb1p,
    float* __restrict__ vs1, float* __restrict__ vd1,
    float* __restrict__ vs2, float* __restrict__ vd2,
    float* __restrict__ vb1, float* __restrict__ vb2,
    float* __restrict__ gw2f, float* __restrict__ glwf,
    float* __restrict__ gb2f, float* __restrict__ glbf,
    float* __restrict__ P)
{
    __shared__ int s[256];
    int t = threadIdx.x;
    int b = blockIdx.x;
    if (b < NBE) {
        // local int-dtype detect (odd dwords all zero => int64)
        int nz = 0;
        for (int i = t; i < 1024; i += 256) nz |= ei[2 * i + 1];
        s[t] = nz; __syncthreads();
        for (int d = 128; d > 0; d >>= 1) { if (t < d) s[t] |= s[t + d]; __syncthreads(); }
        int f = (s[0] == 0) ? 1 : 0;
        if (b == 0 && t == 0) iflag[0] = f;
        int e = b * 256 + t;
        if (e < EE) {
            int d = ei[(EE + e) << f];
            atomicAdd(&count[d], 1);
        }
        return;
    }
    // local float-dtype detect on W1
    {
        const unsigned int* w = (const unsigned int*)W1;
        int cnt = 0;
        for (int i = t; i < 1024; i += 256) {
            unsigned int v = w[i];
            int e = (v >> 7) & 0xff;
            cnt += (e >= 100 && e <= 127) ? 1 : 0;
        }
        s[t] = cnt; __syncthreads();
        for (int d = 128; d > 0; d >>= 1) { if (t < d) s[t] += s[t + d]; __syncthreads(); }
    }
    int f = (s[0] >= 512) ? 0 : 1;
    int pb = b - NBE;            // 0..NPREP-1
    if (pb == 0 && t == 0) fflag[0] = f;
    if (pb >= 128) {
        int r = pb - 128;        // 0..49
        int c = t;
        int tb = 0;
        while (r >= c_vbase[tb + 1]) tb++;
        int v = r - c_vbase[tb];
        const void* emb = (tb == 0) ? e0 : (tb == 1) ? e1 : (tb == 2) ? e2 :
                          (tb == 3) ? e3 : (tb == 4) ? e4 : e5;
        float acc = 0.f;
        #pragma unroll 8
        for (int k = 0; k < 64; k++) {
            acc += ldp(emb, v * 64 + k, f) * ldp(W1, (tb * 64 + k) * 256 + c, f);
        }
        P[r * 256 + c] = acc;
        return;
    }
    int i = pb * 256 + t;
    if (i < 32768) { int k = i / 256, n = i % 256; W2T[n * 128 + k] = f2bf(ldp(W2, i, f)); }
    if (i < 16384) {
        int n = i >> 7, k = i & 127;
        float sc = ldp(bng, n, f) * rsqrtf(ldp(bnv, n, f) + 1e-5f);
        GWT[i] = f2bf(ldp(gw1, k * 128 + n, f) * sc);
    }
    if (i < 256) {
        vs1[i] = ldp(as1, i, f); vd1[i] = ldp(ad1, i, f);
        vs2[i] = ldp(as2, i, f); vd2[i] = ldp(ad2, i, f);
    }
    if (i < 128) {
        vb1[i] = ldp(b1, i, f); vb2[i] = ldp(b2, i, f);
        gw2f[i] = ldp(gw2, i, f); glwf[i] = ldp(glw, i, f);
        float sc = ldp(bng, i, f) * rsqrtf(ldp(bnv, i, f) + 1e-5f);
        gb1p[i] = (ldp(gb1, i, f) - ldp(bnm, i, f)) * sc + ldp(bnb, i, f);
    }
    if (i == 0) { gb2f[0] = ldp(gb2, 0, f); glbf[0] = ldp(glb, 0, f); }
}

// ---------------- counting sort scan chain ----------------
__global__ void k_chunk_sum(const int* __restrict__ count, int* __restrict__ csum) {
    __shared__ int s[256];
    int t = threadIdx.x;
    int base = blockIdx.x * 1024 + t * 4;
    int acc = 0;
    #pragma unroll
    for (int j = 0; j < 4; j++) { int n = base + j; if (n < NN) acc += count[n]; }
    s[t] = acc; __syncthreads();
    for (int d = 128; d > 0; d >>= 1) { if (t < d) s[t] += s[t + d]; __syncthreads(); }
    if (t == 0) csum[blockIdx.x] = s[0];
}

__global__ void k_chunk_scan(const int* __restrict__ csum, int* __restrict__ coff, int nchunk) {
    __shared__ int s[256];
    int t = threadIdx.x;
    int v = (t < nchunk) ? csum[t] : 0;
    s[t] = v; __syncthreads();
    for (int d = 1; d < 256; d <<= 1) {
        int x = (t >= d) ? s[t - d] : 0;
        __syncthreads(); s[t] += x; __syncthreads();
    }
    if (t < nchunk) coff[t] = s[t] - v;
}

__global__ void k_scan_write(const int* __restrict__ count, const int* __restrict__ coff,
                             int* __restrict__ offset, int* __restrict__ cursor) {
    __shared__ int s[256];
    int t = threadIdx.x;
    int base = blockIdx.x * 1024 + t * 4;
    int v[4]; int acc = 0;
    #pragma unroll
    for (int j = 0; j < 4; j++) { v[j] = (base + j < NN) ? count[base + j] : 0; acc += v[j]; }
    s[t] = acc; __syncthreads();
    for (int d = 1; d < 256; d <<= 1) {
        int x = (t >= d) ? s[t - d] : 0;
        __syncthreads(); s[t] += x; __syncthreads();
    }
    int pre = s[t] - acc + coff[blockIdx.x];
    #pragma unroll
    for (int j = 0; j < 4; j++) {
        if (base + j < NN) { offset[base + j] = pre; cursor[base + j] = pre; pre += v[j]; }
    }
}

// ---------------- mid: scatter (blocks 0..NBE-1) || embsum (blocks NBE..NBE+NB4-1) ----------------
__global__ __launch_bounds__(256) void k_mid(
    const int* __restrict__ ei, const int* __restrict__ x_raw,
    const int* __restrict__ iflag,
    int* __restrict__ cursor, int* __restrict__ sorted,
    const float* __restrict__ P,
    const float* __restrict__ avs, const float* __restrict__ avd,
    unsigned char* __restrict__ H8,
    float* __restrict__ alS, float* __restrict__ alD)
{
    int b = blockIdx.x;
    int f = iflag[0];
    if (b < NBE) {
        int e = b * 256 + threadIdx.x;
        if (e < EE) {
            int s = ei[e << f];
            int d = ei[(EE + e) << f];
            int p = atomicAdd(&cursor[d], 1);
            sorted[p] = s;
        }
        return;
    }
    int node = (b - NBE) * 4 + (threadIdx.x >> 6);
    if (node >= NN) return;
    int lane = threadIdx.x & 63;
    int c0 = lane * 4;
    int ix[6];
    #pragma unroll
    for (int t = 0; t < 6; t++) ix[t] = (c_vbase[t] + x_raw[(node * 6 + t) << f]) * 256 + c0;
    float4 a = *(const float4*)(P + ix[0]);
    #pragma unroll
    for (int t = 1; t < 6; t++) {
        float4 bb = *(const float4*)(P + ix[t]);
        a.x += bb.x; a.y += bb.y; a.z += bb.z; a.w += bb.w;
    }
    float4 sv = *(const float4*)(avs + c0);
    float4 dv = *(const float4*)(avd + c0);
    float ps = a.x * sv.x + a.y * sv.y + a.z * sv.z + a.w * sv.w;
    float pd = a.x * dv.x + a.y * dv.y + a.z * dv.z + a.w * dv.w;
    #pragma unroll
    for (int m = 1; m < 32; m <<= 1) {
        ps += __shfl_xor(ps, m);
        pd += __shfl_xor(pd, m);
    }
    if ((lane & 31) == 0) {
        int head = lane >> 5;
        alS[node * 2 + head] = ps;
        alD[node * 2 + head] = pd;
    }
    unsigned int u = ((unsigned)fp8_pack2(a.x, a.y) & 0xffffu) |
                     ((unsigned)fp8_pack2(a.z, a.w) << 16);
    *(unsigned int*)(H8 + (size_t)node * 256 + c0) = u;
}

// ---------------- MFMA GEMM (layer 2): M=64 tile, swizzled LDS ----------------
__global__ __launch_bounds__(256, 2) void k_gemm(
    const unsigned short* __restrict__ Ain,
    const unsigned short* __restrict__ WT, unsigned char* __restrict__ H8,
    const float* __restrict__ avs, const float* __restrict__ avd,
    float* __restrict__ alS, float* __restrict__ alD,
    int K)
{
    __shared__ __align__(16) unsigned short As[64 * 32];
    __shared__ __align__(16) unsigned short Bs[256 * 32];
    int tid = threadIdx.x;
    int wave = tid >> 6, lane = tid & 63;
    int quad = lane >> 4, lr = lane & 15;
    int m0 = blockIdx.x * 64;

    f32x4 zero4 = {0.f, 0.f, 0.f, 0.f};
    f32x4 acc[16];
    #pragma unroll
    for (int j = 0; j < 16; j++) acc[j] = zero4;

    for (int k0 = 0; k0 < K; k0 += 32) {
        {
            int row = tid >> 2, part = tid & 3;
            int gr = m0 + row; if (gr >= NN) gr = NN - 1;
            int g = ((row >> 4) << 6) + (part << 4) + (row & 15);
            g ^= (part << 1);
            *(uint4*)(&As[g * 8]) = *(const uint4*)(Ain + (size_t)gr * K + k0 + part * 8);
        }
        #pragma unroll
        for (int i = 0; i < 4; i++) {
            int idx = tid + i * 256;
            int row = idx >> 2, part = idx & 3;
            int g = ((row >> 4) << 6) + (part << 4) + (row & 15);
            g ^= (part << 1);
            *(uint4*)(&Bs[g * 8]) =
                *(const uint4*)(WT + (size_t)row * K + k0 + part * 8);
        }
        __syncthreads();

        int sw = (quad << 1);
        bf16x8 af0 = *(const bf16x8*)(&As[((wave * 64 + lane) ^ sw) * 8]);
        #pragma unroll
        for (int ni = 0; ni < 16; ni++) {
            bf16x8 bfv = *(const bf16x8*)(&Bs[((ni * 64 + lane) ^ sw) * 8]);
            acc[ni] = __builtin_amdgcn_mfma_f32_16x16x32_bf16(af0, bfv, acc[ni], 0, 0, 0);
        }
        __syncthreads();
    }

    float svv[16], dvv[16];
    #pragma unroll
    for (int ni = 0; ni < 16; ni++) { svv[ni] = avs[ni * 16 + lr]; dvv[ni] = avd[ni * 16 + lr]; }
    #pragma unroll
    for (int r = 0; r < 4; r++) {
        int grow = m0 + wave * 16 + quad * 4 + r;
        float ps0 = 0.f, ps1 = 0.f, pd0 = 0.f, pd1 = 0.f;
        if (grow < NN) {
            #pragma unroll
            for (int ni = 0; ni < 16; ni += 2) {
                float v0 = acc[ni][r], v1 = acc[ni + 1][r];
                int pk = fp8_pack2(v0, v1);
                H8[(size_t)grow * 256 + ni * 16 + lr] = (unsigned char)(pk & 0xff);
                H8[(size_t)grow * 256 + (ni + 1) * 16 + lr] = (unsigned char)((pk >> 8) & 0xff);
                if (ni < 8) { ps0 += v0 * svv[ni] + v1 * svv[ni + 1]; pd0 += v0 * dvv[ni] + v1 * dvv[ni + 1]; }
                else        { ps1 += v0 * svv[ni] + v1 * svv[ni + 1]; pd1 += v0 * dvv[ni] + v1 * dvv[ni + 1]; }
            }
        }
        #pragma unroll
        for (int m = 1; m < 16; m <<= 1) {
            ps0 += __shfl_xor(ps0, m); ps1 += __shfl_xor(ps1, m);
            pd0 += __shfl_xor(pd0, m); pd1 += __shfl_xor(pd1, m);
        }
        if (lr == 0 && grow < NN) {
            alS[grow * 2 + 0] = ps0; alS[grow * 2 + 1] = ps1;
            alD[grow * 2 + 0] = pd0; alD[grow * 2 + 1] = pd1;
        }
    }
}

// ---------------- fused edge-weight + segment aggregation ----------------
__device__ __forceinline__ float edge_w(float e) {
    e = e > 0.f ? e : 0.2f * e;
    e = fminf(fmaxf(e, -60.f), 60.f);
    return __expf(e);
}
__global__ __launch_bounds__(256) void k_agg(const unsigned char* __restrict__ H8,
                                             const float* __restrict__ alS, const float* __restrict__ alD,
                                             const int* __restrict__ sorted, const int* __restrict__ offs,
                                             const int* __restrict__ cnts,
                                             const float* __restrict__ bias,
                                             unsigned short* __restrict__ Out) {
    __shared__ uint4 lw[4][64];
    int wid = threadIdx.x >> 6;
    int node = blockIdx.x * 4 + wid;
    if (node >= NN) return;
    int lane = threadIdx.x & 63;
    int head = lane >> 5;
    float2 adv = *(const float2*)(alD + node * 2);
    float myAd = head ? adv.y : adv.x;
    const unsigned char* Hl = H8 + lane * 4;

    float ws = edge_w(alS[node * 2 + head] + myAd);
    unsigned int qv = *(const unsigned int*)(Hl + ((unsigned)node << 8));
    f32x2 lo, hi; fp8_dec4v(qv, lo, hi);
    float den = ws;
    f32x2 wsv = {ws, ws};
    f32x2 n01 = lo * wsv, n23 = hi * wsv;

    int off = offs[node], cnt = cnts[node];
    for (int c = 0; c < cnt; c += 64) {
        int m = cnt - c; if (m > 64) m = 64;
        int j = off + c + (lane < m ? lane : 0);
        int s = sorted[j];
        float2 asv = *(const float2*)(alS + s * 2);
        float w0 = edge_w(asv.x + adv.x);
        float w1 = edge_w(asv.y + adv.y);
        lw[wid][lane] = make_uint4((unsigned)s << 8, __float_as_uint(w0), __float_as_uint(w1), 0u);
        int i = 0;
        for (; i + 8 <= m; i += 8) {
            uint4 e[8];
            #pragma unroll
            for (int u = 0; u < 8; u++) e[u] = lw[wid][i + u];
            unsigned q[8];
            #pragma unroll
            for (int u = 0; u < 8; u++) q[u] = *(const unsigned int*)(Hl + e[u].x);
            #pragma unroll
            for (int u = 0; u < 8; u++) {
                float w = __uint_as_float(head ? e[u].z : e[u].y);
                f32x2 l, h; fp8_dec4v(q[u], l, h);
                den += w;
                f32x2 wv = {w, w};
                n01 += l * wv;
                n23 += h * wv;
            }
        }
        for (; i + 4 <= m; i += 4) {
            uint4 e[4];
            #pragma unroll
            for (int u = 0; u < 4; u++) e[u] = lw[wid][i + u];
            unsigned q[4];
            #pragma unroll
            for (int u = 0; u < 4; u++) q[u] = *(const unsigned int*)(Hl + e[u].x);
            #pragma unroll
            for (int u = 0; u < 4; u++) {
                float w = __uint_as_float(head ? e[u].z : e[u].y);
                f32x2 l, h; fp8_dec4v(q[u], l, h);
                den += w;
                f32x2 wv = {w, w};
                n01 += l * wv;
                n23 += h * wv;
            }
        }
        for (; i < m; i++) {
            uint4 e0 = lw[wid][i];
            unsigned q0 = *(const unsigned int*)(Hl + e0.x);
            float w = __uint_as_float(head ? e0.z : e0.y);
            f32x2 l, h; fp8_dec4v(q0, l, h);
            den += w;
            f32x2 wv = {w, w};
            n01 += l * wv;
            n23 += h * wv;
        }
    }
    float inv = 1.f / den;
    float v0 = n01[0] * inv, v1 = n01[1] * inv, v2 = n23[0] * inv, v3 = n23[1] * inv;
    float o0 = 0.5f * (v0 + __shfl_xor(v0, 32));
    float o1 = 0.5f * (v1 + __shfl_xor(v1, 32));
    float o2 = 0.5f * (v2 + __shfl_xor(v2, 32));
    float o3 = 0.5f * (v3 + __shfl_xor(v3, 32));
    if (lane < 32) {
        int c = lane * 4;
        float4 bv = *(const float4*)(bias + c);
        o0 = sigmoidf_(o0 + bv.x);
        o1 = sigmoidf_(o1 + bv.y);
        o2 = sigmoidf_(o2 + bv.z);
        o3 = sigmoidf_(o3 + bv.w);
        uint2 pv;
        pv.x = (unsigned int)f2bf(o0) | ((unsigned int)f2bf(o1) << 16);
        pv.y = (unsigned int)f2bf(o2) | ((unsigned int)f2bf(o3) << 16);
        *(uint2*)(Out + (size_t)node * 128 + c) = pv;
    }
}

// ---------------- fused gate+pool ----------------
__global__ __launch_bounds__(256, 2) void k_gate(
    const unsigned short* __restrict__ Obuf,
    const unsigned short* __restrict__ GWT,
    const float* __restrict__ gb1p, const float* __restrict__ gw2f,
    const float* __restrict__ gb2f,
    const int* __restrict__ batch_raw, const int* __restrict__ iflag,
    float* __restrict__ accv, float* __restrict__ accw)
{
    __shared__ __align__(16) unsigned short As[64 * 128];
    __shared__ __align__(16) unsigned short Bs[128 * 128];
    __shared__ float wlds[64];
    __shared__ int gid[64];
    int tid = threadIdx.x;
    int wave = tid >> 6, lane = tid & 63;
    int quad = lane >> 4, lr = lane & 15;
    int m0 = blockIdx.x * 64;

    #pragma unroll
    for (int i = 0; i < 4; i++) {
        int idx = tid + i * 256;
        int row = idx >> 4, p = idx & 15;
        int gr = m0 + row; if (gr >= NN) gr = NN - 1;
        int slot = row * 16 + (p & 8) + ((p & 7) ^ (row & 7));
        *(uint4*)(&As[slot * 8]) = *(const uint4*)(Obuf + (size_t)gr * 128 + p * 8);
    }
    #pragma unroll
    for (int i = 0; i < 8; i++) {
        int idx = tid + i * 256;
        int row = idx >> 4, p = idx & 15;
        int slot = row * 16 + (p & 8) + ((p & 7) ^ (row & 7));
        *(uint4*)(&Bs[slot * 8]) = *(const uint4*)(GWT + (size_t)row * 128 + p * 8);
    }
    if (tid < 64) {
        int nd = m0 + tid; if (nd >= NN) nd = NN - 1;
        gid[tid] = batch_raw[nd << iflag[0]];
    }
    __syncthreads();

    f32x4 zero4 = {0.f, 0.f, 0.f, 0.f};
    f32x4 acc[8];
    #pragma unroll
    for (int j = 0; j < 8; j++) acc[j] = zero4;

    int rowa = wave * 16 + lr;
    #pragma unroll
    for (int k0 = 0; k0 < 128; k0 += 32) {
        int kb = k0 >> 3;
        int pa = (kb & 8) + (((kb & 7) + quad) ^ (lr & 7));
        bf16x8 af0 = *(const bf16x8*)(&As[(rowa * 16 + pa) * 8]);
        #pragma unroll
        for (int ni = 0; ni < 8; ni++) {
            int rowb = ni * 16 + lr;
            bf16x8 bfv = *(const bf16x8*)(&Bs[(rowb * 16 + pa) * 8]);
            acc[ni] = __builtin_amdgcn_mfma_f32_16x16x32_bf16(af0, bfv, acc[ni], 0, 0, 0);
        }
    }

    float gb[8], gw[8];
    #pragma unroll
    for (int ni = 0; ni < 8; ni++) { gb[ni] = gb1p[ni * 16 + lr]; gw[ni] = gw2f[ni * 16 + lr]; }
    #pragma unroll
    for (int r = 0; r < 4; r++) {
        int row = wave * 16 + quad * 4 + r;
        float part = 0.f;
        #pragma unroll
        for (int ni = 0; ni < 8; ni++) {
            float v = acc[ni][r] + gb[ni];
            v = v > 0.f ? v : 0.f;
            part += v * gw[ni];
        }
        #pragma unroll
        for (int m = 1; m < 16; m <<= 1) part += __shfl_xor(part, m);
        if (lr == 0) {
            float w = (m0 + row < NN) ? __expf(part + gb2f[0]) : 0.f;
            wlds[row] = w;
        }
    }
    __syncthreads();

    int ch = tid & 127;
    int r0 = (tid >> 7) * 32;
    int p = ch >> 3, ip = ch & 7;
    float accum = 0.f, aw = 0.f;
    int g = -1;
    for (int rr = 0; rr < 32; rr++) {
        int row = r0 + rr;
        int gi = gid[row];
        float w = wlds[row];
        if (gi != g) {
            if (g >= 0) {
                atomicAdd(&accv[g * 128 + ch], accum);
                if (ch == 0) atomicAdd(&accw[g], aw);
            }
            g = gi; accum = 0.f; aw = 0.f;
        }
        int slot = row * 16 + (p & 8) + ((p & 7) ^ (row & 7));
        float val = bf2f(As[slot * 8 + ip]);
        accum += w * val;
        if (ch == 0) aw += w;
    }
    if (g >= 0) {
        atomicAdd(&accv[g * 128 + ch], accum);
        if (ch == 0) atomicAdd(&accw[g], aw);
    }
}

// ---------------- final head ----------------
__global__ __launch_bounds__(128) void k_pfin(const float* __restrict__ accv,
                                              const float* __restrict__ accw,
                                              const float* __restrict__ glwf,
                                              const float* __restrict__ glbf,
                                              const int* __restrict__ fflag,
                                              void* __restrict__ out) {
    __shared__ float sv[128];
    int g = blockIdx.x, t = threadIdx.x;
    float pooled = accv[g * 128 + t] / (accw[g] + 1e-16f);
    sv[t] = pooled * glwf[t];
    __syncthreads();
    for (int s = 64; s > 0; s >>= 1) { if (t < s) sv[t] += sv[t + s]; __syncthreads(); }
    if (t == 0) {
        float r = sigmoidf_(sv[0] + glbf[0]);
        if (fflag[0]) ((float*)out)[g] = r;
        else ((unsigned short*)out)[g] = f2bf(r);
    }
}

extern "C" void kernel_launch(void* const* d_in, const int* in_sizes, int n_in,
                              void* d_out, int out_size, void* d_ws, size_t ws_size,
                              hipStream_t stream) {
    const int* x_raw  = (const int*)d_in[0];
    const int* ei_raw = (const int*)d_in[1];
    const int* b_raw  = (const int*)d_in[3];

    char* p = (char*)d_ws;
    auto alloc = [&](size_t bytes) { void* r = (void*)p; p += (bytes + 255) & ~(size_t)255; return r; };
    unsigned char* H8   = (unsigned char*)alloc((size_t)NN * 256);
    unsigned short* Obuf = (unsigned short*)alloc((size_t)NN * 128 * 2);
    float* alS   = (float*)alloc((size_t)NN * 2 * 4);
    float* alD   = (float*)alloc((size_t)NN * 2 * 4);
    char* z0 = p;
    int* count   = (int*)alloc((size_t)NN * 4);
    float* accv  = (float*)alloc(GG * 128 * 4);
    float* accw  = (float*)alloc(GG * 4);
    size_t zlen = (size_t)(p - z0);
    int* offs    = (int*)alloc((size_t)NN * 4);
    int* cursor  = (int*)alloc((size_t)NN * 4);
    int* sorted  = (int*)alloc((size_t)EE * 4);
    int* csum    = (int*)alloc(256 * 4);
    int* coff    = (int*)alloc(256 * 4);
    unsigned short* W2T  = (unsigned short*)alloc(256 * 128 * 2);
    unsigned short* GWT  = (unsigned short*)alloc(128 * 128 * 2);
    float* gb1p = (float*)alloc(128 * 4);
    float* Ptab = (float*)alloc(50 * 256 * 4);
    int* iflag  = (int*)alloc(256);
    int* fflag  = (int*)alloc(256);
    float* vs1  = (float*)alloc(256 * 4);
    float* vd1  = (float*)alloc(256 * 4);
    float* vs2  = (float*)alloc(256 * 4);
    float* vd2  = (float*)alloc(256 * 4);
    float* vb1  = (float*)alloc(128 * 4);
    float* vb2  = (float*)alloc(128 * 4);
    float* gw2f = (float*)alloc(128 * 4);
    float* glwf = (float*)alloc(128 * 4);
    float* gb2f = (float*)alloc(4);
    float* glbf = (float*)alloc(4);

    const int NCHUNK = (NN + 1023) / 1024;
    const int NBM = (NN + 63) / 64;

    hipMemsetAsync(z0, 0, zlen, stream);

    // front: hist || prep (local dtype detection)
    k_front<<<NBE + NPREP, 256, 0, stream>>>(
        ei_raw, count, iflag, fflag,
        d_in[4], d_in[5], d_in[6], d_in[7], d_in[8], d_in[9],
        d_in[10], d_in[14],
        d_in[11], d_in[12], d_in[13], d_in[15], d_in[16], d_in[17],
        d_in[18], d_in[19], d_in[20], d_in[21], d_in[22], d_in[23],
        d_in[24], d_in[25], d_in[26], d_in[27],
        W2T, GWT, gb1p,
        vs1, vd1, vs2, vd2, vb1, vb2, gw2f, glwf, gb2f, glbf, Ptab);

    k_chunk_sum<<<NCHUNK, 256, 0, stream>>>(count, csum);
    k_chunk_scan<<<1, 256, 0, stream>>>(csum, coff, NCHUNK);
    k_scan_write<<<NCHUNK, 256, 0, stream>>>(count, coff, offs, cursor);

    // mid: scatter || layer-1 embsum
    k_mid<<<NBE + NB4, 256, 0, stream>>>(ei_raw, x_raw, iflag, cursor, sorted,
                                         Ptab, vs1, vd1, H8, alS, alD);

    // layer 1 aggregate
    k_agg<<<NB4, 256, 0, stream>>>(H8, alS, alD, sorted, offs, count, vb1, Obuf);

    // layer 2
    k_gemm<<<NBM, 256, 0, stream>>>(Obuf, W2T, H8, vs2, vd2, alS, alD, 128);
    k_agg<<<NB4, 256, 0, stream>>>(H8, alS, alD, sorted, offs, count, vb2, Obuf);

    // fused pooling head
    k_gate<<<NBM, 256, 0, stream>>>(Obuf, GWT, gb1p, gw2f, gb2f, b_raw, iflag, accv, accw);
    k_pfin<<<GG, 128, 0, stream>>>(accv, accw, glwf, glbf, fflag, d_out);
}